// Round 7
// baseline (235.973 us; speedup 1.0000x reference)
//
#include <hip/hip_runtime.h>
#include <hip/hip_bf16.h>

typedef __bf16 bf16_t;
typedef __bf16 bf16x4 __attribute__((ext_vector_type(4)));
typedef __bf16 bf16x8 __attribute__((ext_vector_type(8)));
typedef float  f32x4  __attribute__((ext_vector_type(4)));

// ---------------------------------------------------------------- helpers
__device__ __forceinline__ void gload_lds16(const void* g, void* l)
{
    __builtin_amdgcn_global_load_lds((__attribute__((address_space(1))) void*)g,
                                     (__attribute__((address_space(3))) void*)l,
                                     16, 0, 0);
}

// ---------------------------------------------------------------- fused fp32 -> bf16 casts (x1|x2 -> xcat, W1, W2)
__global__ __launch_bounds__(256) void cast_all(const float* __restrict__ x1, const float* __restrict__ x2,
                                                const float* __restrict__ W1, const float* __restrict__ W2,
                                                bf16_t* __restrict__ xcatb, bf16_t* __restrict__ W1b,
                                                bf16_t* __restrict__ W2b)
{
    const size_t i  = ((size_t)blockIdx.x * 256 + threadIdx.x) * 4;
    const size_t M4 = 1ull << 22;              // 4M elements per region
    const size_t r  = i >> 22;
    const size_t off = i & (M4 - 1);
    const float* src; bf16_t* dst;
    if (r == 0)      { src = x1; dst = xcatb; }
    else if (r == 1) { src = x2; dst = xcatb + M4; }
    else if (r == 2) { src = W1; dst = W1b; }
    else             { src = W2; dst = W2b; }
    f32x4 v = *(const f32x4*)(src + off);
    bf16x4 o;
    o[0] = (bf16_t)v[0]; o[1] = (bf16_t)v[1]; o[2] = (bf16_t)v[2]; o[3] = (bf16_t)v[3];
    *(bf16x4*)(dst + off) = o;
}

// ---------------------------------------------------------------- NT GEMM: 128x128 tile, BK=64, 8 waves (2m x 4n)
// Each wave: 64x32 output via 4x2 frags of 16x16x32 MFMA. 16 waves/CU (4/SIMD) at 2 blocks/CU.
// mode 1: + per-mblock column sum/sumsq partials (BN stats), from exact fp32 acc.
// mode 2: + rn_m*rn_n scaling (row-normalize folded), per-nblock row argmax + row LSE partials (self excluded).
// mode 3: + per-nblock row sum-of-squares partials (L2 row norms), from exact fp32 acc.
// c_bf16: write C as bf16 (else fp32).
__global__ __launch_bounds__(512, 4) void gemm_bt(
    const bf16_t* __restrict__ A, const bf16_t* __restrict__ B,
    const float* __restrict__ bias, void* __restrict__ Cv,
    int N, int K, int rows_per_batch, long long b_batch_stride,
    int mode, int c_bf16,
    float* __restrict__ ps, float* __restrict__ ps2,
    float* __restrict__ rsq, const float* __restrict__ rnv,
    unsigned long long* __restrict__ pkey, float* __restrict__ lseP)
{
    __shared__ bf16_t lsA[128 * 64];
    __shared__ bf16_t lsB[128 * 64];
    __shared__ float  cs2[8][32];                 // mode1: per-wave col sums
    __shared__ float  cq2[8][32];                 // mode1: per-wave col sumsqs
    __shared__ float  rq2[8][64];                 // mode3: per-wave row sumsqs
    __shared__ float  ls2[8][64];                 // mode2: per-wave row exp-sums
    __shared__ unsigned long long kv2[8][64];     // mode2: per-wave row argmax keys
    const int tid  = threadIdx.x;
    const int lane = tid & 63;
    const int wave = tid >> 6;
    const int wm   = (wave >> 2) * 64;            // m-half
    const int wn   = (wave & 3) * 32;             // n-quarter
    const int m0   = blockIdx.y * 128;
    const int n0   = blockIdx.x * 128;
    const bf16_t* Bb = B + (long long)(m0 / rows_per_batch) * b_batch_stride;

    f32x4 acc[4][2] = {};

    const int srow = tid >> 3;        // staging: 512 threads cover 64 rows x 8 chunks of 16B
    const int scol = (tid & 7) * 8;
    for (int kt = 0; kt < K; kt += 64) {
#pragma unroll
        for (int i = 0; i < 2; ++i) {
            const int r = i * 64 + srow;
            // LDS dest = wave-uniform base + lane*16 (linear, required for global_load_lds)
            gload_lds16(A  + (size_t)(m0 + r) * K + kt + scol, lsA + r * 64 + scol);
            gload_lds16(Bb + (size_t)(n0 + r) * K + kt + scol, lsB + r * 64 + scol);
        }
        __syncthreads();  // compiler drains vmcnt before barrier
#pragma unroll
        for (int ks = 0; ks < 2; ++ks) {
            const int kk = ks * 32 + (lane >> 4) * 8;
            bf16x8 af[4], bfr[2];
#pragma unroll
            for (int f = 0; f < 4; ++f)
                af[f]  = *(const bf16x8*)&lsA[(wm + f * 16 + (lane & 15)) * 64 + kk];
#pragma unroll
            for (int g = 0; g < 2; ++g)
                bfr[g] = *(const bf16x8*)&lsB[(wn + g * 16 + (lane & 15)) * 64 + kk];
#pragma unroll
            for (int fm = 0; fm < 4; ++fm)
#pragma unroll
                for (int fn = 0; fn < 2; ++fn)
                    acc[fm][fn] = __builtin_amdgcn_mfma_f32_16x16x32_bf16(af[fm], bfr[fn], acc[fm][fn], 0, 0, 0);
        }
        __syncthreads();
    }

    // ---- mode2: fold row-normalization in: acc[m][n] *= rn[m]*rn[n]
    if (mode == 2) {
        const int rnb = (m0 >> 11) * 2048;   // branch base for B-side rn
#pragma unroll
        for (int fm = 0; fm < 4; ++fm) {
            const int mb = m0 + wm + fm * 16 + ((lane >> 4) << 2);
            const f32x4 rm = *(const f32x4*)&rnv[mb];
#pragma unroll
            for (int fn = 0; fn < 2; ++fn) {
                const float rc = rnv[rnb + n0 + wn + fn * 16 + (lane & 15)];
#pragma unroll
                for (int r = 0; r < 4; ++r)
                    acc[fm][fn][r] *= rm[r] * rc;
            }
        }
    }

    // ---- C write (+bias). C/D layout: col = lane&15, row = (lane>>4)*4 + reg  [m89-verified]
#pragma unroll
    for (int fm = 0; fm < 4; ++fm) {
        const int rb = m0 + wm + fm * 16 + ((lane >> 4) << 2);
#pragma unroll
        for (int fn = 0; fn < 2; ++fn) {
            const int colg = n0 + wn + fn * 16 + (lane & 15);
            const float bv = bias ? bias[colg] : 0.0f;
            if (c_bf16) {
                bf16_t* Cb = (bf16_t*)Cv;
#pragma unroll
                for (int r = 0; r < 4; ++r)
                    Cb[(size_t)(rb + r) * N + colg] = (bf16_t)(acc[fm][fn][r] + bv);
            } else {
                float* Cf = (float*)Cv;
#pragma unroll
                for (int r = 0; r < 4; ++r)
                    Cf[(size_t)(rb + r) * N + colg] = acc[fm][fn][r] + bv;
            }
        }
    }

    if (mode == 1) {
        // column sum/sumsq over this block's 128 rows. Col c covered by waves q=(c>>5) and q+4.
#pragma unroll
        for (int fn = 0; fn < 2; ++fn) {
            const int cl32 = fn * 16 + (lane & 15);          // 0..31 within wave's col range
            const float bv = bias[n0 + wn + cl32];
            float s = 0.f, q = 0.f;
#pragma unroll
            for (int fm = 0; fm < 4; ++fm)
#pragma unroll
                for (int r = 0; r < 4; ++r) {
                    const float v = acc[fm][fn][r] + bv;
                    s += v; q += v * v;
                }
            s += __shfl_xor(s, 16); q += __shfl_xor(q, 16);  // sum over lane>>4 row groups
            s += __shfl_xor(s, 32); q += __shfl_xor(q, 32);
            if (lane < 16) { cs2[wave][cl32] = s; cq2[wave][cl32] = q; }
        }
        __syncthreads();
        if (tid < 128) {
            const int qv = tid >> 5, cl = tid & 31;
            ps [(size_t)blockIdx.y * 2048 + n0 + tid] = cs2[qv][cl] + cs2[qv + 4][cl];
            ps2[(size_t)blockIdx.y * 2048 + n0 + tid] = cq2[qv][cl] + cq2[qv + 4][cl];
        }
    } else if (mode == 3) {
        // row sum-of-squares of (acc+bias). Row rl covered by waves (rl>>6)*4 .. +3.
#pragma unroll
        for (int fm = 0; fm < 4; ++fm)
#pragma unroll
            for (int r = 0; r < 4; ++r) {
                float q = 0.f;
#pragma unroll
                for (int fn = 0; fn < 2; ++fn) {
                    const float v = acc[fm][fn][r] + bias[n0 + wn + fn * 16 + (lane & 15)];
                    q += v * v;
                }
                q += __shfl_xor(q, 1); q += __shfl_xor(q, 2);   // sum over 16 cols
                q += __shfl_xor(q, 4); q += __shfl_xor(q, 8);
                if ((lane & 15) == 0)
                    rq2[wave][fm * 16 + ((lane >> 4) << 2) + r] = q;
            }
        __syncthreads();
        if (tid < 128) {
            const int wlo = (tid >> 6) * 4, rl = tid & 63;
            rsq[(size_t)blockIdx.x * 4096 + m0 + tid] =
                rq2[wlo][rl] + rq2[wlo + 1][rl] + rq2[wlo + 2][rl] + rq2[wlo + 3][rl];
        }
    } else if (mode == 2) {
        // row argmax + row LSE over this block's 128 cols (scaled acc), self excluded.
#pragma unroll
        for (int fm = 0; fm < 4; ++fm)
#pragma unroll
            for (int r = 0; r < 4; ++r) {
                const int rl   = fm * 16 + ((lane >> 4) << 2) + r;   // 0..63 within wave's rows
                const int self = (m0 + wm + rl) & 2047;
                float best = -1.0e38f; int bi = 0x7fffffff; float se = 0.f;
#pragma unroll
                for (int fn = 0; fn < 2; ++fn) {
                    const int cg = n0 + wn + fn * 16 + (lane & 15);
                    const float v = acc[fm][fn][r];
                    if (cg != self) {
                        se += expf(10.0f * v);
                        if (v > best) { best = v; bi = cg; }
                    }
                }
#pragma unroll
                for (int st = 1; st <= 8; st <<= 1) {   // reduce over the 16-lane col group
                    const float ov = __shfl_xor(best, st);
                    const int   oi = __shfl_xor(bi, st);
                    if (ov > best || (ov == best && oi < bi)) { best = ov; bi = oi; }
                    se += __shfl_xor(se, st);
                }
                if ((lane & 15) == 0) {
                    unsigned u = __float_as_uint(best);
                    u = (u & 0x80000000u) ? ~u : (u | 0x80000000u);
                    kv2[wave][rl] = ((unsigned long long)u << 32) | (unsigned)(~bi);
                    ls2[wave][rl] = se;
                }
            }
        __syncthreads();
        if (tid < 128) {
            const int wlo = (tid >> 6) * 4, rl = tid & 63;
            unsigned long long k = kv2[wlo][rl];
#pragma unroll
            for (int j = 1; j < 4; ++j) { const unsigned long long v = kv2[wlo + j][rl]; k = v > k ? v : k; }
            pkey[(size_t)blockIdx.x * 4096 + m0 + tid] = k;
            lseP[(size_t)blockIdx.x * 4096 + m0 + tid] =
                ls2[wlo][rl] + ls2[wlo + 1][rl] + ls2[wlo + 2][rl] + ls2[wlo + 3][rl];
        }
    }
}

// ---------------------------------------------------------------- BN finalize from 16 per-mblock partials
__global__ __launch_bounds__(256) void bn_final2(const float* __restrict__ ps, const float* __restrict__ ps2,
                                                 float* __restrict__ mu, float* __restrict__ rinv)
{
    const int c = blockIdx.x * 256 + threadIdx.x;  // 0..4095
    const int b = c >> 11, col = c & 2047;
    float s = 0.f, s2 = 0.f;
    for (int i = 0; i < 16; ++i) {
        s  += ps [(size_t)(b * 16 + i) * 2048 + col];
        s2 += ps2[(size_t)(b * 16 + i) * 2048 + col];
    }
    const float m = s * (1.0f / 2048.0f);
    const float v = s2 * (1.0f / 2048.0f) - m * m;   // biased var
    mu[c]   = m;
    rinv[c] = rsqrtf(v + 1e-5f);
}

// ---------------------------------------------------------------- BN apply + ReLU on bf16 h -> bf16 hn
__global__ __launch_bounds__(256) void bn_apply(const bf16_t* __restrict__ h, const float* __restrict__ mu,
                                                const float* __restrict__ rinv, const float* __restrict__ gamma,
                                                const float* __restrict__ beta, bf16_t* __restrict__ out)
{
    const size_t base = ((size_t)blockIdx.x * 256 + threadIdx.x) * 8;
    const int col = (int)(base & 2047);
    const int br  = (int)(base >> 22);              // (row>>11)
    bf16x8 v = *(const bf16x8*)(h + base);
    bf16x8 o;
#pragma unroll
    for (int j = 0; j < 8; ++j) {
        const int c = col + j;
        const float f = (float)v[j];
        const float t = (f - mu[br * 2048 + c]) * rinv[br * 2048 + c] * gamma[c] + beta[c];
        o[j] = (bf16_t)fmaxf(t, 0.0f);
    }
    *(bf16x8*)(out + base) = o;
}

// ---------------------------------------------------------------- rn[r] = 1/max(||o_r||, 1e-12) from 16 partials
__global__ __launch_bounds__(256) void norm_final(const float* __restrict__ rsq, float* __restrict__ rn)
{
    const int r = blockIdx.x * 256 + threadIdx.x;   // 0..4095
    float s = 0.f;
    for (int nb = 0; nb < 16; ++nb) s += rsq[(size_t)nb * 4096 + r];
    rn[r] = 1.0f / fmaxf(sqrtf(s), 1e-12f);
}

// ---------------------------------------------------------------- CC (argmax-combine folded), early-exit, 1 block/branch
__global__ __launch_bounds__(1024) void cc_labels(const unsigned long long* __restrict__ pkey,
                                                  int* __restrict__ labg)
{
    __shared__ int A_[2048];
    __shared__ int Bn[2048];
    __shared__ int Y_[2048];
    __shared__ int chg;
    const int br = blockIdx.x;
    const int t = threadIdx.x;
    if (t == 0) chg = 0;
    // fold: per-row max over the 16 n-block partials -> kNN neighbor
    for (int i = t; i < 2048; i += 1024) {
        const int row = br * 2048 + i;
        unsigned long long k = 0ull;
        for (int nb = 0; nb < 16; ++nb) {
            const unsigned long long v = pkey[(size_t)nb * 4096 + row];
            k = (v > k) ? v : k;
        }
        Y_[i] = (int)~((unsigned)(k & 0xFFFFFFFFull));
        A_[i] = i;
    }
    __syncthreads();
    // deterministic monotone map: early exit at fixpoint == exact 32-iter result
    for (int it = 0; it < 32; ++it) {
        for (int i = t; i < 2048; i += 1024) Bn[i] = min(A_[i], A_[Y_[i]]);   // ln = min(l, l[y])
        __syncthreads();
        for (int i = t; i < 2048; i += 1024) atomicMin(&Bn[Y_[i]], A_[i]);    // ln = ln.at[y].min(l)
        __syncthreads();
        int ch = 0;
        for (int i = t; i < 2048; i += 1024) {
            const int b = Bn[i];
            const int nv = min(b, Bn[b]);                                      // pointer jump
            if (nv != A_[i]) { ch = 1; A_[i] = nv; }
        }
        if (ch) atomicOr(&chg, 1);
        __syncthreads();
        const int c = chg;
        __syncthreads();
        if (t == 0) chg = 0;
        if (!c) break;
    }
    for (int i = t; i < 2048; i += 1024) labg[br * 2048 + i] = A_[i];
}

// ---------------------------------------------------------------- per-row term from bf16 sim + exact LSE partials
__global__ __launch_bounds__(256) void loss_rows(const bf16_t* __restrict__ simb, const int* __restrict__ labels,
                                                 const float* __restrict__ lseP, float* __restrict__ terms)
{
    const int row = blockIdx.x;
    const int br  = row >> 11;
    const int* lab = labels + ((1 - br) << 11);  // mask from the OTHER branch's labels
    const int self = row & 2047;
    const int li = lab[self];
    const int t = threadIdx.x;
    const bf16x8 v8 = *(const bf16x8*)(simb + (size_t)row * 2048 + t * 8);
    float psum = 0.f; int pc = 0;
#pragma unroll
    for (int j = 0; j < 8; ++j) {
        const int c = t * 8 + j;
        if (c == self) continue;
        if (lab[c] == li) { psum += 10.0f * (float)v8[j]; pc++; }
    }
    __shared__ float PS[256]; __shared__ int PC[256];
    PS[t] = psum; PC[t] = pc;
    __syncthreads();
    for (int off = 128; off; off >>= 1) {
        if (t < off) { PS[t] += PS[t + off]; PC[t] += PC[t + off]; }
        __syncthreads();
    }
    if (t == 0) {
        float se = 0.f;
        for (int nb = 0; nb < 16; ++nb) se += lseP[(size_t)nb * 4096 + row];
        terms[row] = logf(se) - PS[0] / (float)PC[0];
    }
}

// ---------------------------------------------------------------- final deterministic reduce
__global__ __launch_bounds__(1024) void final_reduce(const float* __restrict__ terms, float* __restrict__ out)
{
    const int t = threadIdx.x;
    float s = terms[t] + terms[t + 1024] + terms[t + 2048] + terms[t + 3072];
    __shared__ float S[1024];
    S[t] = s;
    __syncthreads();
    for (int off = 512; off; off >>= 1) { if (t < off) S[t] += S[t + off]; __syncthreads(); }
    if (t == 0) out[0] = S[0] * (1.0f / 4096.0f);   // (L1+L2)/2, each mean over 2048 rows
}

// ---------------------------------------------------------------- launch
extern "C" void kernel_launch(void* const* d_in, const int* in_sizes, int n_in,
                              void* d_out, int out_size, void* d_ws, size_t ws_size,
                              hipStream_t stream)
{
    const float* x1    = (const float*)d_in[0];
    const float* x2    = (const float*)d_in[1];
    const float* W1    = (const float*)d_in[2];
    const float* b1    = (const float*)d_in[3];
    const float* gamma = (const float*)d_in[4];
    const float* beta  = (const float*)d_in[5];
    const float* W2    = (const float*)d_in[6];
    const float* b2    = (const float*)d_in[7];

    char* ws = (char*)d_ws;
    const size_t MB = 1024ull * 1024ull;
    const size_t NN = 2048ull * 2048ull;
    // Region plan:
    //  [0,8M)   W1b   (dead after GEMM1)      } sim_bf16 [0,16M) written by GEMM3 after both dead
    //  [8,16M)  W2b   (dead after GEMM2)      }
    //  [16,32M) xcatb -> hnb
    //  [32,48M) h_bf16  (GEMM1 C; dead after bn_apply)
    //  [64,80M) o_bf16  (GEMM2 C; read by GEMM3)
    //  [80M..)  partials + small buffers
    bf16_t* W1b    = (bf16_t*)(ws + 0);
    bf16_t* W2b    = (bf16_t*)(ws + 8 * MB);
    bf16_t* xcatb  = (bf16_t*)(ws + 16 * MB);
    bf16_t* hnb    = (bf16_t*)(ws + 16 * MB);
    bf16_t* hb16   = (bf16_t*)(ws + 32 * MB);
    bf16_t* ob16   = (bf16_t*)(ws + 64 * MB);
    bf16_t* simb   = (bf16_t*)(ws + 0);
    float*  psA    = (float*)(ws + 80 * MB);               // [32][2048] col sums
    float*  psB    = psA + 32 * 2048;                       // [32][2048] col sumsq
    float*  rsq    = psB + 32 * 2048;                       // [16][4096] row sumsq
    float*  mu     = rsq + 16 * 4096;                       // [2][2048]
    float*  rinv   = mu + 4096;
    float*  rn     = rinv + 4096;                           // [4096]
    float*  lseP   = rn + 4096;                             // [16][4096] row exp-sum partials
    unsigned long long* pkey = (unsigned long long*)(lseP + 16 * 4096);  // [16][4096]
    int*    labels = (int*)(pkey + 16 * 4096);
    float*  terms  = (float*)(labels + 4096);

    // fused casts
    cast_all<<<16384, 256, 0, stream>>>(x1, x2, W1, W2, xcatb, W1b, W2b);

    // h = xcat @ W1^T + b1 (M=4096,N=2048,K=2048) -> bf16, fused BN-stat partials (exact fp32 acc)
    gemm_bt<<<dim3(16, 32), 512, 0, stream>>>(xcatb, W1b, b1, hb16, 2048, 2048, 1 << 30, 0,
                                              1, 1, psA, psB, nullptr, nullptr, nullptr, nullptr);
    bn_final2<<<16, 256, 0, stream>>>(psA, psB, mu, rinv);
    bn_apply<<<4096, 256, 0, stream>>>(hb16, mu, rinv, gamma, beta, hnb);

    // o = hn @ W2^T + b2 -> bf16, fused row-sumsq partials (exact fp32 acc)
    gemm_bt<<<dim3(16, 32), 512, 0, stream>>>(hnb, W2b, b2, ob16, 2048, 2048, 1 << 30, 0,
                                              3, 1, nullptr, nullptr, rsq, nullptr, nullptr, nullptr);
    norm_final<<<16, 256, 0, stream>>>(rsq, rn);

    // sim = [o1@o1^T ; o2@o2^T] * rn_m*rn_n -> bf16, fused row-argmax + row-LSE partials (exact fp32 acc)
    gemm_bt<<<dim3(16, 32), 512, 0, stream>>>(ob16, ob16, nullptr, simb, 2048, 2048, 2048, (long long)NN,
                                              2, 1, nullptr, nullptr, nullptr, rn, pkey, lseP);

    // CC (argmax folded, early-exit) -> loss
    cc_labels<<<2, 1024, 0, stream>>>(pkey, labels);
    loss_rows<<<4096, 256, 0, stream>>>(simb, labels, lseP, terms);
    final_reduce<<<1, 1024, 0, stream>>>(terms, (float*)d_out);
}